// Round 5
// baseline (124.538 us; speedup 1.0000x reference)
//
#include <hip/hip_runtime.h>
#include <hip/hip_bf16.h>

// Problem constants (B=4, Tq=Tk=512, Q=K=1024, C=256)
#define M_ROWS 2048   // B*Tq = B*Tk
#define KDIM   1024
#define CDIM   256
#define TQ     512
#define TK     512

#define GBM 64        // m rows per block (gemm)
#define GBN 32        // c cols per block (gemm)
#define GBK 32        // k per stage

#define QT 64         // bahdanau q-tile
#define KT 32         // bahdanau k-tile

// 2*log2(e): tanh(x) = 1 - 2/(exp2(2log2e * x) + 1)
#define SCALE2LOG2E 2.8853900817779268f

typedef __attribute__((ext_vector_type(8))) short short8;
typedef __attribute__((ext_vector_type(4))) float floatx4;
typedef __attribute__((ext_vector_type(2))) float f32x2;

__device__ __forceinline__ short2 cvt2(float x, float y) {
    __hip_bfloat162 h = __float22bfloat162_rn(make_float2(x, y));
    short2 r;
    __builtin_memcpy(&r, &h, sizeof(r));
    return r;
}

// MFMA GEMM producing E[c][m] = exp2(S * sum_k A[m][k]*W[k][c]),
// q-side additionally prescaled by s_c = -0.5/w_c.
// D[i=c][j=m] via mfma_f32_16x16x32_bf16:
//   A-op: A[i=lane&15][k=quad*8+jj] = W^T  -> Ws[c][k] k-contiguous
//   B-op: B[k=quad*8+jj][j=lane&15] = A^T  -> As[m][k] k-contiguous
//   D   : col j = lane&15, row i = quad*4+reg
__global__ __launch_bounds__(256) void gemm_mfma_kernel(
    const float* __restrict__ Aq, const float* __restrict__ Ak,
    const float* __restrict__ Wq, const float* __restrict__ Wk,
    const float* __restrict__ w_attn,
    float* __restrict__ Eq, float* __restrict__ Ek)
{
    __shared__ short As[GBM][GBK + 8];   // [m][k] pad->40 shorts (80B rows)
    __shared__ short Ws[GBN][GBK + 8];   // [c][k]

    const int z = blockIdx.z;
    const float* A = z ? Ak : Aq;
    const float* W = z ? Wk : Wq;
    float*       E = z ? Ek : Eq;

    const int t    = threadIdx.x;
    const int lane = t & 63;
    const int wave = t >> 6;
    const int m0   = blockIdx.x * GBM;
    const int n0   = blockIdx.y * GBN;

    const int ar = t >> 2;            // A stage: row 0..63
    const int ac = (t & 3) * 8;       // A stage: k col 0,8,16,24
    const int wr = t >> 3;            // W stage: k row 0..31
    const int wc = (t & 7) * 4;       // W stage: c col 0,4,..,28

    const int iw = wave & 1;          // c subtile (16)
    const int jw = wave >> 1;         // m subtile pair (32)
    const int li = lane & 15;
    const int qd = lane >> 4;

    floatx4 acc0 = {0.f, 0.f, 0.f, 0.f};
    floatx4 acc1 = {0.f, 0.f, 0.f, 0.f};

    // prefetch k0 = 0
    float4 a0 = *(const float4*)&A[(size_t)(m0 + ar) * KDIM + ac];
    float4 a1 = *(const float4*)&A[(size_t)(m0 + ar) * KDIM + ac + 4];
    float4 w0 = *(const float4*)&W[(size_t)wr * CDIM + n0 + wc];

    for (int k0 = 0; k0 < KDIM; k0 += GBK) {
        __syncthreads();                       // previous-iter LDS reads done
        short2 p0 = cvt2(a0.x, a0.y), p1 = cvt2(a0.z, a0.w);
        short2 p2 = cvt2(a1.x, a1.y), p3 = cvt2(a1.z, a1.w);
        short8 av = { p0.x, p0.y, p1.x, p1.y, p2.x, p2.y, p3.x, p3.y };
        *(short8*)&As[ar][ac] = av;
        short2 u0 = cvt2(w0.x, w0.y), u1 = cvt2(w0.z, w0.w);
        Ws[wc + 0][wr] = u0.x;                 // 80B row stride
        Ws[wc + 1][wr] = u0.y;
        Ws[wc + 2][wr] = u1.x;
        Ws[wc + 3][wr] = u1.y;
        __syncthreads();
        if (k0 + GBK < KDIM) {                 // prefetch next stage
            a0 = *(const float4*)&A[(size_t)(m0 + ar) * KDIM + k0 + GBK + ac];
            a1 = *(const float4*)&A[(size_t)(m0 + ar) * KDIM + k0 + GBK + ac + 4];
            w0 = *(const float4*)&W[(size_t)(k0 + GBK + wr) * CDIM + n0 + wc];
        }
        short8 af  = *(const short8*)&Ws[iw * 16 + li][qd * 8];
        short8 bf0 = *(const short8*)&As[jw * 32 + li][qd * 8];
        short8 bf1 = *(const short8*)&As[jw * 32 + 16 + li][qd * 8];
        acc0 = __builtin_amdgcn_mfma_f32_16x16x32_bf16(af, bf0, acc0, 0, 0, 0);
        acc1 = __builtin_amdgcn_mfma_f32_16x16x32_bf16(af, bf1, acc1, 0, 0, 0);
    }

    #pragma unroll
    for (int r = 0; r < 4; ++r) {
        const int c = n0 + iw * 16 + qd * 4 + r;
        float scale = z ? 1.0f : (-0.5f / w_attn[c]);
        float v0 = __builtin_amdgcn_exp2f(acc0[r] * SCALE2LOG2E) * scale;
        float v1 = __builtin_amdgcn_exp2f(acc1[r] * SCALE2LOG2E) * scale;
        E[(size_t)c * M_ROWS + m0 + jw * 32 + li]      = v0;
        E[(size_t)c * M_ROWS + m0 + jw * 32 + 16 + li] = v1;
    }
}

// scores[b][q][k] = (b_attn + sum_c w_c) + sum_c rcp(f_c),
//   f_c = fma(Eqs[c][q], Ek[c][k], s_c),  Eqs = s_c*e^{2 q2ctx}, Ek = e^{2 k2ctx}
// Pairing: rcp(f1)+rcp(f2) = (f1+f2)*rcp(f1*f2)  -> 1 transcendental per 2 c's.
// 64q x 32k tile, 256 thr, 4q x 2k per thread; consecutive lanes -> consecutive k.
__global__ __launch_bounds__(256) void bahdanau_kernel(
    const float* __restrict__ Eqs, const float* __restrict__ Ek,
    const float* __restrict__ w_attn, const float* __restrict__ b_attn,
    float* __restrict__ out)
{
    __shared__ float qs[64][QT + 4];  // [c][q] stride 68
    __shared__ float ks[64][KT + 4];  // [c][k] stride 36
    __shared__ float sl[CDIM];        // s_c = -0.5/w_c
    __shared__ float partial[4];      // per-wave w sums

    const int t  = threadIdx.x;
    const int b  = blockIdx.z;
    const int q0 = blockIdx.x * QT;
    const int k0 = blockIdx.y * KT;
    const int gq = b * TQ + q0;
    const int gk = b * TK + k0;
    const int tq = (t >> 4) * 4;      // q base (broadcast LDS reads)
    const int tk = (t & 15) * 2;      // k base (consecutive lanes -> consecutive k)

    const int qlr = t >> 4;           // q-stage c-row 0..15 (+16j)
    const int qlc = (t & 15) * 4;     // q-stage col*4
    const int klr = t >> 3;           // k-stage c-row 0..31 (+32j)
    const int klc = (t & 7) * 4;      // k-stage col*4

    {   // prologue: s_c and sum(w); CDIM == blockDim.x == 256
        float wv = w_attn[t];
        sl[t] = -0.5f / wv;
        float sum = wv;
        #pragma unroll
        for (int o = 32; o >= 1; o >>= 1) sum += __shfl_down(sum, o);
        if ((t & 63) == 0) partial[t >> 6] = sum;
    }

    // prefetch chunk 0
    float4 qv[4], kv[2];
    #pragma unroll
    for (int j = 0; j < 4; ++j)
        qv[j] = *(const float4*)&Eqs[(size_t)(qlr + 16 * j) * M_ROWS + gq + qlc];
    #pragma unroll
    for (int j = 0; j < 2; ++j)
        kv[j] = *(const float4*)&Ek[(size_t)(klr + 32 * j) * M_ROWS + gk + klc];

    f32x2 acc[4] = {{0.f, 0.f}, {0.f, 0.f}, {0.f, 0.f}, {0.f, 0.f}};

    for (int ch = 0; ch < 4; ++ch) {
        __syncthreads();              // previous chunk's compute done
        #pragma unroll
        for (int j = 0; j < 4; ++j) *(float4*)&qs[qlr + 16 * j][qlc] = qv[j];
        #pragma unroll
        for (int j = 0; j < 2; ++j) *(float4*)&ks[klr + 32 * j][klc] = kv[j];
        __syncthreads();
        if (ch < 3) {                 // prefetch next chunk (waits at next store)
            const int c1 = (ch + 1) * 64;
            #pragma unroll
            for (int j = 0; j < 4; ++j)
                qv[j] = *(const float4*)&Eqs[(size_t)(c1 + qlr + 16 * j) * M_ROWS + gq + qlc];
            #pragma unroll
            for (int j = 0; j < 2; ++j)
                kv[j] = *(const float4*)&Ek[(size_t)(c1 + klr + 32 * j) * M_ROWS + gk + klc];
        }
        const int cb = ch * 64;
        #pragma unroll 4
        for (int c = 0; c < 64; c += 2) {
            float s1v = sl[cb + c], s2v = sl[cb + c + 1];
            f32x2 s1 = {s1v, s1v}, s2 = {s2v, s2v};
            float4 q1 = *(const float4*)&qs[c][tq];
            float4 q2 = *(const float4*)&qs[c + 1][tq];
            f32x2 k1 = *(const f32x2*)&ks[c][tk];
            f32x2 k2 = *(const f32x2*)&ks[c + 1][tk];
            {
                f32x2 f1 = __builtin_elementwise_fma((f32x2){q1.x, q1.x}, k1, s1);
                f32x2 f2 = __builtin_elementwise_fma((f32x2){q2.x, q2.x}, k2, s2);
                f32x2 g = f1 * f2, h = f1 + f2;
                f32x2 r = {__builtin_amdgcn_rcpf(g.x), __builtin_amdgcn_rcpf(g.y)};
                acc[0] = __builtin_elementwise_fma(h, r, acc[0]);
            }
            {
                f32x2 f1 = __builtin_elementwise_fma((f32x2){q1.y, q1.y}, k1, s1);
                f32x2 f2 = __builtin_elementwise_fma((f32x2){q2.y, q2.y}, k2, s2);
                f32x2 g = f1 * f2, h = f1 + f2;
                f32x2 r = {__builtin_amdgcn_rcpf(g.x), __builtin_amdgcn_rcpf(g.y)};
                acc[1] = __builtin_elementwise_fma(h, r, acc[1]);
            }
            {
                f32x2 f1 = __builtin_elementwise_fma((f32x2){q1.z, q1.z}, k1, s1);
                f32x2 f2 = __builtin_elementwise_fma((f32x2){q2.z, q2.z}, k2, s2);
                f32x2 g = f1 * f2, h = f1 + f2;
                f32x2 r = {__builtin_amdgcn_rcpf(g.x), __builtin_amdgcn_rcpf(g.y)};
                acc[2] = __builtin_elementwise_fma(h, r, acc[2]);
            }
            {
                f32x2 f1 = __builtin_elementwise_fma((f32x2){q1.w, q1.w}, k1, s1);
                f32x2 f2 = __builtin_elementwise_fma((f32x2){q2.w, q2.w}, k2, s2);
                f32x2 g = f1 * f2, h = f1 + f2;
                f32x2 r = {__builtin_amdgcn_rcpf(g.x), __builtin_amdgcn_rcpf(g.y)};
                acc[3] = __builtin_elementwise_fma(h, r, acc[3]);
            }
        }
    }

    const float bias2 = *b_attn + partial[0] + partial[1] + partial[2] + partial[3];
    float* o = out + ((size_t)b * TQ + q0 + tq) * TK + k0 + tk;
    #pragma unroll
    for (int i = 0; i < 4; ++i)
        *(float2*)&o[i * TK] = make_float2(acc[i].x + bias2, acc[i].y + bias2);
}

extern "C" void kernel_launch(void* const* d_in, const int* in_sizes, int n_in,
                              void* d_out, int out_size, void* d_ws, size_t ws_size,
                              hipStream_t stream) {
    const float* query  = (const float*)d_in[0];
    const float* key    = (const float*)d_in[1];
    const float* Wq     = (const float*)d_in[2];
    const float* Wk     = (const float*)d_in[3];
    const float* w_attn = (const float*)d_in[4];
    const float* b_attn = (const float*)d_in[5];
    float* out = (float*)d_out;

    float* Eqs = (float*)d_ws;                 // 256 x 2048 fp32 = 2 MB
    float* Ek  = Eqs + (size_t)CDIM * M_ROWS;  // 256 x 2048 fp32 = 2 MB

    dim3 gemm_grid(M_ROWS / GBM, CDIM / GBN, 2);   // 32 x 8 x 2 = 512 blocks
    gemm_mfma_kernel<<<gemm_grid, 256, 0, stream>>>(query, key, Wq, Wk, w_attn, Eqs, Ek);

    dim3 main_grid(TQ / QT, TK / KT, 4);           // 8 x 16 x 4 = 512 blocks
    bahdanau_kernel<<<main_grid, 256, 0, stream>>>(Eqs, Ek, w_attn, b_attn, out);
}

// Round 6
// 122.667 us; speedup vs baseline: 1.0152x; 1.0152x over previous
//
#include <hip/hip_runtime.h>
#include <hip/hip_bf16.h>

// Problem constants (B=4, Tq=Tk=512, Q=K=1024, C=256)
#define M_ROWS 2048   // B*Tq = B*Tk
#define KDIM   1024
#define CDIM   256
#define TQ     512
#define TK     512

#define GBM 64        // m rows per block (gemm)
#define GBN 32        // c cols per block (gemm)
#define GBK 32        // k per stage

// 2*log2(e): tanh(x) = 1 - 2/(exp2(2log2e * x) + 1)
#define SCALE2LOG2E 2.8853900817779268f

typedef __attribute__((ext_vector_type(8))) short short8;
typedef __attribute__((ext_vector_type(4))) float floatx4;
typedef __attribute__((ext_vector_type(2))) float f32x2;

__device__ __forceinline__ short2 cvt2(float x, float y) {
    __hip_bfloat162 h = __float22bfloat162_rn(make_float2(x, y));
    short2 r;
    __builtin_memcpy(&r, &h, sizeof(r));
    return r;
}

__device__ __forceinline__ f32x2 splat2(float x) { return (f32x2){x, x}; }

// MFMA GEMM producing E[c][m] = exp2(S * sum_k A[m][k]*W[k][c]),
// q-side additionally prescaled by s_c = -0.5/w_c.   (unchanged from R5)
__global__ __launch_bounds__(256) void gemm_mfma_kernel(
    const float* __restrict__ Aq, const float* __restrict__ Ak,
    const float* __restrict__ Wq, const float* __restrict__ Wk,
    const float* __restrict__ w_attn,
    float* __restrict__ Eq, float* __restrict__ Ek)
{
    __shared__ short As[GBM][GBK + 8];   // [m][k] pad->40 shorts (80B rows)
    __shared__ short Ws[GBN][GBK + 8];   // [c][k]

    const int z = blockIdx.z;
    const float* A = z ? Ak : Aq;
    const float* W = z ? Wk : Wq;
    float*       E = z ? Ek : Eq;

    const int t    = threadIdx.x;
    const int lane = t & 63;
    const int wave = t >> 6;
    const int m0   = blockIdx.x * GBM;
    const int n0   = blockIdx.y * GBN;

    const int ar = t >> 2;            // A stage: row 0..63
    const int ac = (t & 3) * 8;       // A stage: k col 0,8,16,24
    const int wr = t >> 3;            // W stage: k row 0..31
    const int wc = (t & 7) * 4;       // W stage: c col 0,4,..,28

    const int iw = wave & 1;          // c subtile (16)
    const int jw = wave >> 1;         // m subtile pair (32)
    const int li = lane & 15;
    const int qd = lane >> 4;

    floatx4 acc0 = {0.f, 0.f, 0.f, 0.f};
    floatx4 acc1 = {0.f, 0.f, 0.f, 0.f};

    // prefetch k0 = 0
    float4 a0 = *(const float4*)&A[(size_t)(m0 + ar) * KDIM + ac];
    float4 a1 = *(const float4*)&A[(size_t)(m0 + ar) * KDIM + ac + 4];
    float4 w0 = *(const float4*)&W[(size_t)wr * CDIM + n0 + wc];

    for (int k0 = 0; k0 < KDIM; k0 += GBK) {
        __syncthreads();                       // previous-iter LDS reads done
        short2 p0 = cvt2(a0.x, a0.y), p1 = cvt2(a0.z, a0.w);
        short2 p2 = cvt2(a1.x, a1.y), p3 = cvt2(a1.z, a1.w);
        short8 av = { p0.x, p0.y, p1.x, p1.y, p2.x, p2.y, p3.x, p3.y };
        *(short8*)&As[ar][ac] = av;
        short2 u0 = cvt2(w0.x, w0.y), u1 = cvt2(w0.z, w0.w);
        Ws[wc + 0][wr] = u0.x;                 // 80B row stride
        Ws[wc + 1][wr] = u0.y;
        Ws[wc + 2][wr] = u1.x;
        Ws[wc + 3][wr] = u1.y;
        __syncthreads();
        if (k0 + GBK < KDIM) {                 // prefetch next stage
            a0 = *(const float4*)&A[(size_t)(m0 + ar) * KDIM + k0 + GBK + ac];
            a1 = *(const float4*)&A[(size_t)(m0 + ar) * KDIM + k0 + GBK + ac + 4];
            w0 = *(const float4*)&W[(size_t)(k0 + GBK + wr) * CDIM + n0 + wc];
        }
        short8 af  = *(const short8*)&Ws[iw * 16 + li][qd * 8];
        short8 bf0 = *(const short8*)&As[jw * 32 + li][qd * 8];
        short8 bf1 = *(const short8*)&As[jw * 32 + 16 + li][qd * 8];
        acc0 = __builtin_amdgcn_mfma_f32_16x16x32_bf16(af, bf0, acc0, 0, 0, 0);
        acc1 = __builtin_amdgcn_mfma_f32_16x16x32_bf16(af, bf1, acc1, 0, 0, 0);
    }

    #pragma unroll
    for (int r = 0; r < 4; ++r) {
        const int c = n0 + iw * 16 + qd * 4 + r;
        float scale = z ? 1.0f : (-0.5f / w_attn[c]);
        float v0 = __builtin_amdgcn_exp2f(acc0[r] * SCALE2LOG2E) * scale;
        float v1 = __builtin_amdgcn_exp2f(acc1[r] * SCALE2LOG2E) * scale;
        E[(size_t)c * M_ROWS + m0 + jw * 32 + li]      = v0;
        E[(size_t)c * M_ROWS + m0 + jw * 32 + 16 + li] = v1;
    }
}

// scores[b][q][k] = (b_attn + sum_c w_c) + sum_c rcp(f_c),
//   f_c = fma(Eqs[c][q], Ek[c][k], s_c),  Eqs = s_c*e^{2 q2ctx}, Ek = e^{2 k2ctx}
// 4-way pairing: 1/f1+1/f2+1/f3+1/f4 = ((f1+f2)f3f4+(f3+f4)f1f2)*rcp(f1f2f3f4)
//   -> 1 transcendental per 4 c's; 12 pk-VALU + 2 rcp per 8 element-products.
// 32q x 32k tile, 1024 blocks (full occupancy), 2q x 2k per thread,
// consecutive lanes -> consecutive k (coalesced stores, broadcast q-reads).
__global__ __launch_bounds__(256) void bahdanau_kernel(
    const float* __restrict__ Eqs, const float* __restrict__ Ek,
    const float* __restrict__ w_attn, const float* __restrict__ b_attn,
    float* __restrict__ out)
{
    __shared__ float qs[64][36];          // [c][q] stride 36
    __shared__ float ks[64][36];          // [c][k]
    __shared__ __align__(16) float sl[CDIM];  // s_c = -0.5/w_c
    __shared__ float partial[4];          // per-wave w sums

    const int t  = threadIdx.x;
    const int b  = blockIdx.z;
    const int q0 = blockIdx.x * 32;
    const int k0 = blockIdx.y * 32;
    const int gq = b * TQ + q0;
    const int gk = b * TK + k0;
    const int tq = (t >> 4) * 2;      // q base (broadcast LDS reads)
    const int tk = (t & 15) * 2;      // k base (lanes -> consecutive k)

    const int lr = t >> 3;            // stage c-row 0..31 (+32j)
    const int lc = (t & 7) * 4;       // stage col*4

    {   // prologue: s_c and sum(w); CDIM == blockDim.x == 256
        float wv = w_attn[t];
        sl[t] = -0.5f / wv;
        float sum = wv;
        #pragma unroll
        for (int o = 32; o >= 1; o >>= 1) sum += __shfl_down(sum, o);
        if ((t & 63) == 0) partial[t >> 6] = sum;
    }

    // prefetch chunk 0
    float4 qv[2], kv[2];
    #pragma unroll
    for (int j = 0; j < 2; ++j) {
        qv[j] = *(const float4*)&Eqs[(size_t)(lr + 32 * j) * M_ROWS + gq + lc];
        kv[j] = *(const float4*)&Ek [(size_t)(lr + 32 * j) * M_ROWS + gk + lc];
    }

    f32x2 accA = {0.f, 0.f};          // q row tq,   k pair
    f32x2 accB = {0.f, 0.f};          // q row tq+1, k pair

    for (int ch = 0; ch < 4; ++ch) {
        __syncthreads();              // previous chunk's compute done
        #pragma unroll
        for (int j = 0; j < 2; ++j) {
            *(float4*)&qs[lr + 32 * j][lc] = qv[j];
            *(float4*)&ks[lr + 32 * j][lc] = kv[j];
        }
        __syncthreads();
        if (ch < 3) {                 // prefetch next chunk
            const int c1 = (ch + 1) * 64;
            #pragma unroll
            for (int j = 0; j < 2; ++j) {
                qv[j] = *(const float4*)&Eqs[(size_t)(c1 + lr + 32 * j) * M_ROWS + gq + lc];
                kv[j] = *(const float4*)&Ek [(size_t)(c1 + lr + 32 * j) * M_ROWS + gk + lc];
            }
        }
        const int cb = ch * 64;
        #pragma unroll
        for (int cc = 0; cc < 64; cc += 4) {
            float4 s4 = *(const float4*)&sl[cb + cc];
            f32x2 q1 = *(const f32x2*)&qs[cc + 0][tq];
            f32x2 q2 = *(const f32x2*)&qs[cc + 1][tq];
            f32x2 q3 = *(const f32x2*)&qs[cc + 2][tq];
            f32x2 q4 = *(const f32x2*)&qs[cc + 3][tq];
            f32x2 k1 = *(const f32x2*)&ks[cc + 0][tk];
            f32x2 k2 = *(const f32x2*)&ks[cc + 1][tk];
            f32x2 k3 = *(const f32x2*)&ks[cc + 2][tk];
            f32x2 k4 = *(const f32x2*)&ks[cc + 3][tk];
            {   // group A: q component .x
                f32x2 f1 = __builtin_elementwise_fma(splat2(q1.x), k1, splat2(s4.x));
                f32x2 f2 = __builtin_elementwise_fma(splat2(q2.x), k2, splat2(s4.y));
                f32x2 f3 = __builtin_elementwise_fma(splat2(q3.x), k3, splat2(s4.z));
                f32x2 f4 = __builtin_elementwise_fma(splat2(q4.x), k4, splat2(s4.w));
                f32x2 p12 = f1 * f2, p34 = f3 * f4;
                f32x2 s12 = f1 + f2, s34 = f3 + f4;
                f32x2 num = __builtin_elementwise_fma(s12, p34, s34 * p12);
                f32x2 den = p12 * p34;
                f32x2 r = {__builtin_amdgcn_rcpf(den.x), __builtin_amdgcn_rcpf(den.y)};
                accA = __builtin_elementwise_fma(num, r, accA);
            }
            {   // group B: q component .y
                f32x2 f1 = __builtin_elementwise_fma(splat2(q1.y), k1, splat2(s4.x));
                f32x2 f2 = __builtin_elementwise_fma(splat2(q2.y), k2, splat2(s4.y));
                f32x2 f3 = __builtin_elementwise_fma(splat2(q3.y), k3, splat2(s4.z));
                f32x2 f4 = __builtin_elementwise_fma(splat2(q4.y), k4, splat2(s4.w));
                f32x2 p12 = f1 * f2, p34 = f3 * f4;
                f32x2 s12 = f1 + f2, s34 = f3 + f4;
                f32x2 num = __builtin_elementwise_fma(s12, p34, s34 * p12);
                f32x2 den = p12 * p34;
                f32x2 r = {__builtin_amdgcn_rcpf(den.x), __builtin_amdgcn_rcpf(den.y)};
                accB = __builtin_elementwise_fma(num, r, accB);
            }
        }
    }

    const float bias2 = *b_attn + partial[0] + partial[1] + partial[2] + partial[3];
    float* o = out + ((size_t)b * TQ + q0 + tq) * TK + k0 + tk;
    *(float2*)&o[0]  = make_float2(accA.x + bias2, accA.y + bias2);
    *(float2*)&o[TK] = make_float2(accB.x + bias2, accB.y + bias2);
}

extern "C" void kernel_launch(void* const* d_in, const int* in_sizes, int n_in,
                              void* d_out, int out_size, void* d_ws, size_t ws_size,
                              hipStream_t stream) {
    const float* query  = (const float*)d_in[0];
    const float* key    = (const float*)d_in[1];
    const float* Wq     = (const float*)d_in[2];
    const float* Wk     = (const float*)d_in[3];
    const float* w_attn = (const float*)d_in[4];
    const float* b_attn = (const float*)d_in[5];
    float* out = (float*)d_out;

    float* Eqs = (float*)d_ws;                 // 256 x 2048 fp32 = 2 MB
    float* Ek  = Eqs + (size_t)CDIM * M_ROWS;  // 256 x 2048 fp32 = 2 MB

    dim3 gemm_grid(M_ROWS / GBM, CDIM / GBN, 2);   // 32 x 8 x 2 = 512 blocks
    gemm_mfma_kernel<<<gemm_grid, 256, 0, stream>>>(query, key, Wq, Wk, w_attn, Eqs, Ek);

    dim3 main_grid(TQ / 32, TK / 32, 4);           // 16 x 16 x 4 = 1024 blocks
    bahdanau_kernel<<<main_grid, 256, 0, stream>>>(Eqs, Ek, w_attn, b_attn, out);
}

// Round 7
// 110.229 us; speedup vs baseline: 1.1298x; 1.1128x over previous
//
#include <hip/hip_runtime.h>
#include <hip/hip_bf16.h>

// Problem constants (B=4, Tq=Tk=512, Q=K=1024, C=256)
#define M_ROWS 2048   // B*Tq = B*Tk
#define KDIM   1024
#define CDIM   256
#define TQ     512
#define TK     512

#define GBM 64        // m rows per block (gemm)
#define GBN 32        // c cols per block (gemm)
#define GBK 32        // k per stage

// 2*log2(e): tanh(x) = 1 - 2/(exp2(2log2e * x) + 1)
#define SCALE2LOG2E 2.8853900817779268f

typedef __attribute__((ext_vector_type(8))) short short8;
typedef __attribute__((ext_vector_type(8))) unsigned short ushort8;
typedef __attribute__((ext_vector_type(4))) float floatx4;
typedef __attribute__((ext_vector_type(2))) float f32x2;

__device__ __forceinline__ short2 cvt2(float x, float y) {
    __hip_bfloat162 h = __float22bfloat162_rn(make_float2(x, y));
    short2 r;
    __builtin_memcpy(&r, &h, sizeof(r));
    return r;
}
__device__ __forceinline__ unsigned short f2bf1(float x) {
    return (unsigned short)cvt2(x, x).x;
}
__device__ __forceinline__ float bf2f(unsigned short u) {
    return __builtin_bit_cast(float, (unsigned)u << 16);
}
__device__ __forceinline__ f32x2 splat2(float x) { return (f32x2){x, x}; }

// MFMA GEMM producing E_bf16[c][m] = bf16(exp2(S * sum_k A[m][k]*W[k][c])),
// q-side additionally prescaled by s_c = -0.5/w_c.
// A-fragment (MFMA B-operand) loaded DIRECTLY from global per lane
// (row = m0+wave*16+(lane&15), k = quad*8..+7) — no LDS staging for A,
// each A element read exactly once. Only W (tiny) goes through LDS.
// Depth-2 register prefetch covers cold-HBM latency (L3 is wiped by the
// harness's 268MB poison fill every iteration).
__global__ __launch_bounds__(256) void gemm_mfma_kernel(
    const float* __restrict__ Aq, const float* __restrict__ Ak,
    const float* __restrict__ Wq, const float* __restrict__ Wk,
    const float* __restrict__ w_attn,
    unsigned short* __restrict__ Eq, unsigned short* __restrict__ Ek)
{
    __shared__ short Ws[GBN][GBK + 8];   // [c][k] 32x40 shorts (80B rows)

    const int z = blockIdx.z;
    const float* A = z ? Ak : Aq;
    const float* W = z ? Wk : Wq;
    unsigned short* E = z ? Ek : Eq;

    const int t    = threadIdx.x;
    const int lane = t & 63;
    const int wave = t >> 6;
    const int m0   = blockIdx.x * GBM;
    const int n0   = blockIdx.y * GBN;

    const int wr = t >> 3;            // W stage: k row 0..31
    const int wc = (t & 7) * 4;       // W stage: c col 0,4,..,28
    const int li = lane & 15;
    const int qd = lane >> 4;

    const int row = m0 + wave * 16 + li;        // this lane's m row
    const float* Arow = A + (size_t)row * KDIM + qd * 8;

    floatx4 acc0 = {0.f, 0.f, 0.f, 0.f};   // c half 0 (c = n0 + qd*4+r)
    floatx4 acc1 = {0.f, 0.f, 0.f, 0.f};   // c half 1 (+16)

    // depth-2 prefetch
    float4 pa0[2], pa1[2], pw[2];
    pa0[0] = *(const float4*)&Arow[0];
    pa1[0] = *(const float4*)&Arow[4];
    pw[0]  = *(const float4*)&W[(size_t)wr * CDIM + n0 + wc];
    pa0[1] = *(const float4*)&Arow[GBK];
    pa1[1] = *(const float4*)&Arow[GBK + 4];
    pw[1]  = *(const float4*)&W[(size_t)(GBK + wr) * CDIM + n0 + wc];

    for (int it = 0; it < KDIM / GBK; ++it) {
        const int s = it & 1;
        __syncthreads();                       // prev-iter Ws reads done
        short2 u0 = cvt2(pw[s].x, pw[s].y), u1 = cvt2(pw[s].z, pw[s].w);
        Ws[wc + 0][wr] = u0.x;
        Ws[wc + 1][wr] = u0.y;
        Ws[wc + 2][wr] = u1.x;
        Ws[wc + 3][wr] = u1.y;
        short2 p0 = cvt2(pa0[s].x, pa0[s].y), p1 = cvt2(pa0[s].z, pa0[s].w);
        short2 p2 = cvt2(pa1[s].x, pa1[s].y), p3 = cvt2(pa1[s].z, pa1[s].w);
        short8 bv = { p0.x, p0.y, p1.x, p1.y, p2.x, p2.y, p3.x, p3.y };
        __syncthreads();                       // Ws ready
        if (it + 2 < KDIM / GBK) {             // refill slot s (just consumed)
            const int k0 = (it + 2) * GBK;
            pa0[s] = *(const float4*)&Arow[k0];
            pa1[s] = *(const float4*)&Arow[k0 + 4];
            pw[s]  = *(const float4*)&W[(size_t)(k0 + wr) * CDIM + n0 + wc];
        }
        short8 af0 = *(const short8*)&Ws[li][qd * 8];
        short8 af1 = *(const short8*)&Ws[16 + li][qd * 8];
        acc0 = __builtin_amdgcn_mfma_f32_16x16x32_bf16(af0, bv, acc0, 0, 0, 0);
        acc1 = __builtin_amdgcn_mfma_f32_16x16x32_bf16(af1, bv, acc1, 0, 0, 0);
    }

    #pragma unroll
    for (int r = 0; r < 4; ++r) {
        const int c0 = n0 + qd * 4 + r;
        const int c1 = c0 + 16;
        float s0 = z ? 1.0f : (-0.5f / w_attn[c0]);
        float s1 = z ? 1.0f : (-0.5f / w_attn[c1]);
        float v0 = __builtin_amdgcn_exp2f(acc0[r] * SCALE2LOG2E) * s0;
        float v1 = __builtin_amdgcn_exp2f(acc1[r] * SCALE2LOG2E) * s1;
        E[(size_t)c0 * M_ROWS + row] = f2bf1(v0);
        E[(size_t)c1 * M_ROWS + row] = f2bf1(v1);
    }
}

// scores[b][q][k] = (b_attn + sum_c w_c) + sum_c rcp(f_c),
//   f_c = fma(Eqs[c][q], Ek[c][k], s_c),  Eqs = s_c*e^{2 q2ctx}, Ek = e^{2 k2ctx}
// 4-way pairing: 1/f1+1/f2+1/f3+1/f4 = ((f1+f2)f3f4+(f3+f4)f1f2)*rcp(f1f2f3f4).
// E is bf16 in global (halved fetch), converted to fp32 during LDS staging.
__global__ __launch_bounds__(256) void bahdanau_kernel(
    const unsigned short* __restrict__ Eqs, const unsigned short* __restrict__ Ek,
    const float* __restrict__ w_attn, const float* __restrict__ b_attn,
    float* __restrict__ out)
{
    __shared__ float qs[64][36];          // [c][q] stride 36
    __shared__ float ks[64][36];          // [c][k]
    __shared__ __align__(16) float sl[CDIM];  // s_c = -0.5/w_c
    __shared__ float partial[4];          // per-wave w sums

    const int t  = threadIdx.x;
    const int b  = blockIdx.z;
    const int q0 = blockIdx.x * 32;
    const int k0 = blockIdx.y * 32;
    const int gq = b * TQ + q0;
    const int gk = b * TK + k0;
    const int tq = (t >> 4) * 2;      // q base (broadcast LDS reads)
    const int tk = (t & 15) * 2;      // k base (lanes -> consecutive k)

    const int lr = t >> 2;            // stage c-row 0..63
    const int lc = (t & 3) * 8;       // stage col*8

    {   // prologue: s_c and sum(w); CDIM == blockDim.x == 256
        float wv = w_attn[t];
        sl[t] = -0.5f / wv;
        float sum = wv;
        #pragma unroll
        for (int o = 32; o >= 1; o >>= 1) sum += __shfl_down(sum, o);
        if ((t & 63) == 0) partial[t >> 6] = sum;
    }

    // prefetch chunk 0 (16B = 8 bf16 per side per thread)
    ushort8 qu = *(const ushort8*)&Eqs[(size_t)lr * M_ROWS + gq + lc];
    ushort8 ku = *(const ushort8*)&Ek [(size_t)lr * M_ROWS + gk + lc];

    f32x2 accA = {0.f, 0.f};          // q row tq,   k pair
    f32x2 accB = {0.f, 0.f};          // q row tq+1, k pair

    for (int ch = 0; ch < 4; ++ch) {
        __syncthreads();              // previous chunk's compute done
        *(float4*)&qs[lr][lc]     = make_float4(bf2f(qu[0]), bf2f(qu[1]), bf2f(qu[2]), bf2f(qu[3]));
        *(float4*)&qs[lr][lc + 4] = make_float4(bf2f(qu[4]), bf2f(qu[5]), bf2f(qu[6]), bf2f(qu[7]));
        *(float4*)&ks[lr][lc]     = make_float4(bf2f(ku[0]), bf2f(ku[1]), bf2f(ku[2]), bf2f(ku[3]));
        *(float4*)&ks[lr][lc + 4] = make_float4(bf2f(ku[4]), bf2f(ku[5]), bf2f(ku[6]), bf2f(ku[7]));
        __syncthreads();
        if (ch < 3) {                 // prefetch next chunk
            const int c1 = (ch + 1) * 64;
            qu = *(const ushort8*)&Eqs[(size_t)(c1 + lr) * M_ROWS + gq + lc];
            ku = *(const ushort8*)&Ek [(size_t)(c1 + lr) * M_ROWS + gk + lc];
        }
        const int cb = ch * 64;
        #pragma unroll
        for (int cc = 0; cc < 64; cc += 4) {
            float4 s4 = *(const float4*)&sl[cb + cc];
            f32x2 q1 = *(const f32x2*)&qs[cc + 0][tq];
            f32x2 q2 = *(const f32x2*)&qs[cc + 1][tq];
            f32x2 q3 = *(const f32x2*)&qs[cc + 2][tq];
            f32x2 q4 = *(const f32x2*)&qs[cc + 3][tq];
            f32x2 k1 = *(const f32x2*)&ks[cc + 0][tk];
            f32x2 k2 = *(const f32x2*)&ks[cc + 1][tk];
            f32x2 k3 = *(const f32x2*)&ks[cc + 2][tk];
            f32x2 k4 = *(const f32x2*)&ks[cc + 3][tk];
            {   // group A: q component .x
                f32x2 f1 = __builtin_elementwise_fma(splat2(q1.x), k1, splat2(s4.x));
                f32x2 f2 = __builtin_elementwise_fma(splat2(q2.x), k2, splat2(s4.y));
                f32x2 f3 = __builtin_elementwise_fma(splat2(q3.x), k3, splat2(s4.z));
                f32x2 f4 = __builtin_elementwise_fma(splat2(q4.x), k4, splat2(s4.w));
                f32x2 p12 = f1 * f2, p34 = f3 * f4;
                f32x2 s12 = f1 + f2, s34 = f3 + f4;
                f32x2 num = __builtin_elementwise_fma(s12, p34, s34 * p12);
                f32x2 den = p12 * p34;
                f32x2 r = {__builtin_amdgcn_rcpf(den.x), __builtin_amdgcn_rcpf(den.y)};
                accA = __builtin_elementwise_fma(num, r, accA);
            }
            {   // group B: q component .y
                f32x2 f1 = __builtin_elementwise_fma(splat2(q1.y), k1, splat2(s4.x));
                f32x2 f2 = __builtin_elementwise_fma(splat2(q2.y), k2, splat2(s4.y));
                f32x2 f3 = __builtin_elementwise_fma(splat2(q3.y), k3, splat2(s4.z));
                f32x2 f4 = __builtin_elementwise_fma(splat2(q4.y), k4, splat2(s4.w));
                f32x2 p12 = f1 * f2, p34 = f3 * f4;
                f32x2 s12 = f1 + f2, s34 = f3 + f4;
                f32x2 num = __builtin_elementwise_fma(s12, p34, s34 * p12);
                f32x2 den = p12 * p34;
                f32x2 r = {__builtin_amdgcn_rcpf(den.x), __builtin_amdgcn_rcpf(den.y)};
                accB = __builtin_elementwise_fma(num, r, accB);
            }
        }
    }

    const float bias2 = *b_attn + partial[0] + partial[1] + partial[2] + partial[3];
    float* o = out + ((size_t)b * TQ + q0 + tq) * TK + k0 + tk;
    *(float2*)&o[0]  = make_float2(accA.x + bias2, accA.y + bias2);
    *(float2*)&o[TK] = make_float2(accB.x + bias2, accB.y + bias2);
}

extern "C" void kernel_launch(void* const* d_in, const int* in_sizes, int n_in,
                              void* d_out, int out_size, void* d_ws, size_t ws_size,
                              hipStream_t stream) {
    const float* query  = (const float*)d_in[0];
    const float* key    = (const float*)d_in[1];
    const float* Wq     = (const float*)d_in[2];
    const float* Wk     = (const float*)d_in[3];
    const float* w_attn = (const float*)d_in[4];
    const float* b_attn = (const float*)d_in[5];
    float* out = (float*)d_out;

    unsigned short* Eqs = (unsigned short*)d_ws;      // 256 x 2048 bf16 = 1 MB
    unsigned short* Ek  = Eqs + (size_t)CDIM * M_ROWS;// 256 x 2048 bf16 = 1 MB

    dim3 gemm_grid(M_ROWS / GBM, CDIM / GBN, 2);   // 32 x 8 x 2 = 512 blocks
    gemm_mfma_kernel<<<gemm_grid, 256, 0, stream>>>(query, key, Wq, Wk, w_attn, Eqs, Ek);

    dim3 main_grid(TQ / 32, TK / 32, 4);           // 16 x 16 x 4 = 1024 blocks
    bahdanau_kernel<<<main_grid, 256, 0, stream>>>(Eqs, Ek, w_attn, b_attn, out);
}